// Round 1
// baseline (318.713 us; speedup 1.0000x reference)
//
#include <hip/hip_runtime.h>
#include <math.h>

#define B_  16
#define L_  2048
#define D_  512
#define K_  7
#define Q_  (B_*L_*D_)   // 16777216 elements per output tensor

// ---------------------------------------------------------------------------
// Kernel A: tiled transpose (B,L,D) -> (B,D,L) for q and k.
// qT/kT live in d_out (scratch; overwritten later by kE / kC).
// ---------------------------------------------------------------------------
__global__ __launch_bounds__(256) void kA(const float* __restrict__ q,
                                          const float* __restrict__ k,
                                          float* __restrict__ qT,
                                          float* __restrict__ kT) {
  __shared__ float tq[32][33];
  __shared__ float tk[32][33];
  const int l0 = blockIdx.x * 32, d0 = blockIdx.y * 32, b = blockIdx.z;
  const int tx = threadIdx.x, ty = threadIdx.y;       // (32,8)
  const size_t ibase = (size_t)b * L_ * D_;
#pragma unroll
  for (int j = 0; j < 4; ++j) {
    const int l = l0 + ty + 8 * j;
    tq[ty + 8 * j][tx] = q[ibase + (size_t)l * D_ + d0 + tx];
    tk[ty + 8 * j][tx] = k[ibase + (size_t)l * D_ + d0 + tx];
  }
  __syncthreads();
  const size_t obase = (size_t)b * D_ * L_;
#pragma unroll
  for (int j = 0; j < 4; ++j) {
    const int d = d0 + ty + 8 * j;
    qT[obase + (size_t)d * L_ + l0 + tx] = tq[tx][ty + 8 * j];
    kT[obase + (size_t)d * L_ + l0 + tx] = tk[tx][ty + 8 * j];
  }
}

// ---------------------------------------------------------------------------
// Kernel B: per-channel circular cross-correlation via FFT.
// z = q + i*k; Z = FFT(z); Hermitian split -> Q,K; S = Q*conj(K);
// corr = Re(IFFT(S)).  Stockham DIF radix-2, natural-order in/out.
// ---------------------------------------------------------------------------
__device__ __forceinline__ void fft_stages(float*& sr, float*& si,
                                           float*& dr, float*& di,
                                           const float* __restrict__ twc,
                                           const float* __restrict__ tws,
                                           int tid, float sgn) {
  for (int st = 0; st < 11; ++st) {
    const int s = 1 << st;
#pragma unroll
    for (int u = 0; u < 4; ++u) {
      const int j   = tid + u * 256;         // butterfly id in [0,1024)
      const int twi = j & ~(s - 1);          // p << st
      const int i0  = j + twi;               // q + s*2p
      const float ar = sr[j],        ai = si[j];
      const float br = sr[j + 1024], bi = si[j + 1024];
      const float c = twc[twi], w = sgn * tws[twi];
      const float tr = ar - br, ti = ai - bi;
      dr[i0]     = ar + br;
      di[i0]     = ai + bi;
      dr[i0 + s] = tr * c - ti * w;
      di[i0 + s] = tr * w + ti * c;
    }
    __syncthreads();
    float* t;
    t = sr; sr = dr; dr = t;
    t = si; si = di; di = t;
  }
}

__global__ __launch_bounds__(256) void kB(const float* __restrict__ qT,
                                          const float* __restrict__ kT,
                                          float* __restrict__ corrT) {
  __shared__ float b0[L_], b1[L_], b2[L_], b3[L_];   // 32 KiB ping-pong
  __shared__ float twc[L_ / 2], tws[L_ / 2];         // 8 KiB twiddles
  const int tid = threadIdx.x;
  const size_t row = (size_t)blockIdx.x * L_;

#pragma unroll
  for (int u = 0; u < 8; ++u) {
    const int i = tid + u * 256;
    b0[i] = qT[row + i];     // real part  = q
    b1[i] = kT[row + i];     // imag part  = k
  }
#pragma unroll
  for (int u = 0; u < 4; ++u) {
    const int t = tid + u * 256;
    const float ang = -6.2831853071795864769f * (float)t * (1.0f / (float)L_);
    float s, c;
    sincosf(ang, &s, &c);    // w = e^{-2*pi*i*t/L} = (c, s)
    twc[t] = c; tws[t] = s;
  }
  __syncthreads();

  float *sr = b0, *si = b1, *dr = b2, *di = b3;
  fft_stages(sr, si, dr, di, twc, tws, tid, 1.0f);   // forward; result in sr/si

  // S[f] = Q[f] * conj(K[f]) from Hermitian split of Z
#pragma unroll
  for (int u = 0; u < 8; ++u) {
    const int f = tid + u * 256;
    const int g = (L_ - f) & (L_ - 1);
    const float ar = sr[f], ai = si[f];
    const float br = sr[g], bi = si[g];
    const float qr = 0.5f * (ar + br), qi = 0.5f * (ai - bi);
    const float kr = 0.5f * (ai + bi), ki = 0.5f * (br - ar);
    dr[f] = qr * kr + qi * ki;
    di[f] = qi * kr - qr * ki;
  }
  __syncthreads();
  { float* t; t = sr; sr = dr; dr = t; t = si; si = di; di = t; }

  fft_stages(sr, si, dr, di, twc, tws, tid, -1.0f);  // inverse (unscaled)

#pragma unroll
  for (int u = 0; u < 8; ++u) {
    const int i = tid + u * 256;
    corrT[row + i] = sr[i] * (1.0f / (float)L_);
  }
}

// ---------------------------------------------------------------------------
// Kernel C: transpose corrT (B,D,L) -> corr_out (B,L,D), plus deterministic
// per-(b, d-tile) column sums for the channel mean.
// ---------------------------------------------------------------------------
__global__ __launch_bounds__(256) void kC(const float* __restrict__ corrT,
                                          float* __restrict__ corrOut,
                                          float* __restrict__ partial) {
  __shared__ float t[32][33];
  const int t0 = blockIdx.x * 32, d0 = blockIdx.y * 32, b = blockIdx.z;
  const int tx = threadIdx.x, ty = threadIdx.y;       // (32,8)
#pragma unroll
  for (int j = 0; j < 4; ++j) {
    const int d = d0 + ty + 8 * j;
    t[ty + 8 * j][tx] = corrT[((size_t)b * D_ + d) * L_ + t0 + tx];
  }
  __syncthreads();
#pragma unroll
  for (int j = 0; j < 4; ++j) {
    const int tt = t0 + ty + 8 * j;
    corrOut[((size_t)b * L_ + tt) * D_ + d0 + tx] = t[tx][ty + 8 * j];
  }
  if (ty == 0) {                                      // 32 threads: one per tau
    float s = 0.f;
#pragma unroll
    for (int i = 0; i < 32; ++i) s += t[i][tx];
    partial[((size_t)b * 16 + blockIdx.y) * L_ + t0 + tx] = s;
  }
}

// ---------------------------------------------------------------------------
// Kernel D: reduce partials -> g[L]; top-7 argmax; per-b softmax weights.
// Single block, fully deterministic.
// ---------------------------------------------------------------------------
__global__ __launch_bounds__(256) void kD(const float* __restrict__ partial,
                                          int* __restrict__ oidx,
                                          float* __restrict__ ow) {
  __shared__ float g[L_];
  __shared__ float rv[256];
  __shared__ int   ri[256];
  __shared__ int   sidx[K_];
  const int tid = threadIdx.x;

  float acc[8] = {0.f, 0.f, 0.f, 0.f, 0.f, 0.f, 0.f, 0.f};
  for (int i = 0; i < 256; ++i) {                    // 256 = B_*16 d-tiles
    const float* rowp = partial + (size_t)i * L_ + tid;
#pragma unroll
    for (int u = 0; u < 8; ++u) acc[u] += rowp[u * 256];
  }
#pragma unroll
  for (int u = 0; u < 8; ++u) g[tid + u * 256] = acc[u];
  __syncthreads();

  for (int it = 0; it < K_; ++it) {
    float bv = -1e30f; int bix = 1 << 30;
#pragma unroll
    for (int u = 0; u < 8; ++u) {
      const int tau = tid + u * 256;
      const float vv = g[tau];
      if (vv > bv || (vv == bv && tau < bix)) { bv = vv; bix = tau; }
    }
    rv[tid] = bv; ri[tid] = bix;
    __syncthreads();
    for (int off = 128; off > 0; off >>= 1) {
      if (tid < off) {
        const float v2 = rv[tid + off]; const int i2 = ri[tid + off];
        if (v2 > rv[tid] || (v2 == rv[tid] && i2 < ri[tid])) {
          rv[tid] = v2; ri[tid] = i2;
        }
      }
      __syncthreads();
    }
    if (tid == 0) { sidx[it] = ri[0]; g[ri[0]] = -3e38f; }
    __syncthreads();
  }

  if (tid < B_) {
    const int b = tid;
    float m[K_]; float mx = -1e30f;
    for (int kk = 0; kk < K_; ++kk) {
      float s = 0.f;
      for (int dt = 0; dt < 16; ++dt)
        s += partial[((size_t)b * 16 + dt) * L_ + sidx[kk]];
      m[kk] = s * (1.0f / 512.0f);                   // mean_value[b, idx_k]
      mx = fmaxf(mx, m[kk]);
    }
    float sum = 0.f;
    for (int kk = 0; kk < K_; ++kk) { m[kk] = expf(m[kk] - mx); sum += m[kk]; }
    const float inv = 1.0f / sum;
    for (int kk = 0; kk < K_; ++kk) ow[b * K_ + kk] = m[kk] * inv;
  }
  if (tid < K_) oidx[tid] = sidx[tid];
}

// ---------------------------------------------------------------------------
// Kernel E: out[b,l,:] = sum_k w[b,k] * v[b, (l+idx[k])%L, :]   (float4)
// ---------------------------------------------------------------------------
__global__ __launch_bounds__(256) void kE(const float4* __restrict__ v4,
                                          const float* __restrict__ w,
                                          const int* __restrict__ idx,
                                          float4* __restrict__ out4) {
  const int bx = blockIdx.x;                   // 0..16383
  const int b  = bx >> 10;                     // uniform per block
  const int l  = ((bx & 1023) << 1) | (threadIdx.x >> 7);
  const int j  = threadIdx.x & 127;            // float4 lane within row (D/4=128)

  float ww[K_]; int rr[K_];
#pragma unroll
  for (int kk = 0; kk < K_; ++kk) {
    ww[kk] = w[b * K_ + kk];
    int r = l + idx[kk];
    if (r >= L_) r -= L_;
    rr[kk] = r;
  }
  const size_t vb = (size_t)b * L_ * 128;
  float4 acc = make_float4(0.f, 0.f, 0.f, 0.f);
#pragma unroll
  for (int kk = 0; kk < K_; ++kk) {
    const float4 vv = v4[vb + (size_t)rr[kk] * 128 + j];
    acc.x += ww[kk] * vv.x; acc.y += ww[kk] * vv.y;
    acc.z += ww[kk] * vv.z; acc.w += ww[kk] * vv.w;
  }
  out4[vb + (size_t)l * 128 + j] = acc;
}

// ---------------------------------------------------------------------------
extern "C" void kernel_launch(void* const* d_in, const int* in_sizes, int n_in,
                              void* d_out, int out_size, void* d_ws, size_t ws_size,
                              hipStream_t stream) {
  const float* q = (const float*)d_in[0];
  const float* k = (const float*)d_in[1];
  const float* v = (const float*)d_in[2];

  float* out     = (float*)d_out;        // final out  [0, Q_)
  float* corrOut = out + Q_;             // final corr [Q_, 2Q_)
  // d_out doubles as transpose scratch (regions dead before overwrite):
  float* qT = out;                       // consumed by kB before kE overwrites
  float* kT = corrOut;                   // consumed by kB before kC overwrites

  float* corrT   = (float*)d_ws;                 // Q_ floats
  float* partial = corrT + Q_;                   // 16*16*2048 = 524288 floats
  int*   oidx    = (int*)(partial + (size_t)B_ * 16 * L_);
  float* ow      = (float*)(oidx + 16);          // 112 floats

  const dim3 thr(32, 8);
  kA<<<dim3(L_ / 32, D_ / 32, B_), thr, 0, stream>>>(q, k, qT, kT);
  kB<<<B_ * D_, 256, 0, stream>>>(qT, kT, corrT);
  kC<<<dim3(L_ / 32, D_ / 32, B_), thr, 0, stream>>>(corrT, corrOut, partial);
  kD<<<1, 256, 0, stream>>>(partial, oidx, ow);
  kE<<<(B_ * L_) / 2, 256, 0, stream>>>((const float4*)v, ow, oidx, (float4*)out);
}

// Round 2
// 207.131 us; speedup vs baseline: 1.5387x; 1.5387x over previous
//
#include <hip/hip_runtime.h>
#include <math.h>

#define B_  16
#define L_  2048
#define D_  512
#define K_  7
#define Q_  (B_*L_*D_)   // 16777216 elements per output tensor

// ---------------------------------------------------------------------------
// Kernel A: tiled transpose (B,L,D) -> (B,D,L) for q and k.
// ---------------------------------------------------------------------------
__global__ __launch_bounds__(256) void kA(const float* __restrict__ q,
                                          const float* __restrict__ k,
                                          float* __restrict__ qT,
                                          float* __restrict__ kT) {
  __shared__ float tq[32][33];
  __shared__ float tk[32][33];
  const int l0 = blockIdx.x * 32, d0 = blockIdx.y * 32, b = blockIdx.z;
  const int tx = threadIdx.x, ty = threadIdx.y;       // (32,8)
  const size_t ibase = (size_t)b * L_ * D_;
#pragma unroll
  for (int j = 0; j < 4; ++j) {
    const int l = l0 + ty + 8 * j;
    tq[ty + 8 * j][tx] = q[ibase + (size_t)l * D_ + d0 + tx];
    tk[ty + 8 * j][tx] = k[ibase + (size_t)l * D_ + d0 + tx];
  }
  __syncthreads();
  const size_t obase = (size_t)b * D_ * L_;
#pragma unroll
  for (int j = 0; j < 4; ++j) {
    const int d = d0 + ty + 8 * j;
    qT[obase + (size_t)d * L_ + l0 + tx] = tq[tx][ty + 8 * j];
    kT[obase + (size_t)d * L_ + l0 + tx] = tk[tx][ty + 8 * j];
  }
}

// ---------------------------------------------------------------------------
// Kernel B: circular cross-correlation via mixed-radix (8,8,8,4) Stockham FFT.
// z = q + i*k; Z = FFT(z); Hermitian split; S = Q*conj(K); corr = Re(IFFT(S))/N
// LDS: two complex ping-pong buffers A,B (32 KiB total), per-buffer XOR
// swizzle so every pass's reads AND writes are bank-conflict-free.
// ---------------------------------------------------------------------------
struct cf { float r, i; };
__device__ __forceinline__ cf cadd(cf a, cf b){ return {a.r+b.r, a.i+b.i}; }
__device__ __forceinline__ cf csub(cf a, cf b){ return {a.r-b.r, a.i-b.i}; }
__device__ __forceinline__ cf cmul(cf a, cf b){ return {a.r*b.r - a.i*b.i, a.r*b.i + a.i*b.r}; }
template<bool INV> __device__ __forceinline__ cf rot90(cf x){
  // multiply by -i (fwd) / +i (inv)
  return INV ? cf{-x.i, x.r} : cf{x.i, -x.r};
}
// buffer A swizzle: bits3-5 ^= bits6-8 (fixes s=8 pass writes; keeps any
// consecutive-lane access conflict-free)
__device__ __forceinline__ int swzA(int a){ return a ^ (((a >> 6) & 7) << 3); }
// buffer B swizzle: bits0-2 ^= bits3-5 ^ bits6-8 (fixes s=1 pass writes)
__device__ __forceinline__ int swzB(int a){ return a ^ (((a >> 3) ^ (a >> 6)) & 7); }

template<bool INV>
__device__ __forceinline__ void dft8(cf a[8], cf b[8]) {
  const float H = 0.70710678118654752440f;
  cf t0 = cadd(a[0],a[4]), t1 = cadd(a[1],a[5]), t2 = cadd(a[2],a[6]), t3 = cadd(a[3],a[7]);
  cf u0 = csub(a[0],a[4]), u1 = csub(a[1],a[5]), u2 = csub(a[2],a[6]), u3 = csub(a[3],a[7]);
  const cf w1 = INV ? cf{H,  H} : cf{ H, -H};
  const cf w3 = INV ? cf{-H, H} : cf{-H, -H};
  u1 = cmul(u1, w1);
  u2 = rot90<INV>(u2);
  u3 = cmul(u3, w3);
  { cf s0 = cadd(t0,t2), s1 = csub(t0,t2), s2 = cadd(t1,t3), s3 = rot90<INV>(csub(t1,t3));
    b[0]=cadd(s0,s2); b[4]=csub(s0,s2); b[2]=cadd(s1,s3); b[6]=csub(s1,s3); }
  { cf s0 = cadd(u0,u2), s1 = csub(u0,u2), s2 = cadd(u1,u3), s3 = rot90<INV>(csub(u1,u3));
    b[1]=cadd(s0,s2); b[5]=csub(s0,s2); b[3]=cadd(s1,s3); b[7]=csub(s1,s3); }
}

// One radix-8 Stockham pass (N=2048, 256 threads, 1 butterfly/thread).
// reads x[j + 256*l]; writes y[j + 7*s*p + s*k] = b_k * w_N^{p*s*k}
template<int LOG2S, bool INV, bool SRC_A>
__device__ __forceinline__ void pass8(const float* __restrict__ sr,
                                      const float* __restrict__ si,
                                      float* __restrict__ dr,
                                      float* __restrict__ di, int tid) {
  const int p = tid >> LOG2S;
  cf a[8], b[8];
#pragma unroll
  for (int l = 0; l < 8; ++l) {
    const int ix = tid + (l << 8);
    const int rs = SRC_A ? swzA(ix) : swzB(ix);
    a[l].r = sr[rs]; a[l].i = si[rs];
  }
  dft8<INV>(a, b);
  const float ANG = -0.0030679615757712823f;  // -2*pi/2048
  float sn, cs;
  __sincosf(ANG * (float)(p << LOG2S), &sn, &cs);
  if (INV) sn = -sn;
  const cf w1{cs, sn};
  cf w = w1;
  b[1] = cmul(b[1], w);
#pragma unroll
  for (int k = 2; k < 8; ++k) { w = cmul(w, w1); b[k] = cmul(b[k], w); }
  const int wb = tid + 7 * (p << LOG2S);
#pragma unroll
  for (int k = 0; k < 8; ++k) {
    const int ix = wb + (k << LOG2S);
    const int ws = SRC_A ? swzB(ix) : swzA(ix);
    dr[ws] = b[k].r; di[ws] = b[k].i;
  }
}

// Final radix-4 pass (s=512): p=0 -> twiddle-free. B -> A, 2 butterflies/thread.
template<bool INV>
__device__ __forceinline__ void pass4_final(const float* __restrict__ sr,
                                            const float* __restrict__ si,
                                            float* __restrict__ dr,
                                            float* __restrict__ di, int tid) {
#pragma unroll
  for (int h = 0; h < 2; ++h) {
    const int j = tid + (h << 8);
    const int r0 = swzB(j), r1 = swzB(j + 512), r2 = swzB(j + 1024), r3 = swzB(j + 1536);
    cf a0{sr[r0], si[r0]}, a1{sr[r1], si[r1]}, a2{sr[r2], si[r2]}, a3{sr[r3], si[r3]};
    cf s0 = cadd(a0,a2), s1 = csub(a0,a2), s2 = cadd(a1,a3), s3 = rot90<INV>(csub(a1,a3));
    cf o0 = cadd(s0,s2), o1 = cadd(s1,s3), o2 = csub(s0,s2), o3 = csub(s1,s3);
    const int w0 = swzA(j), w1x = swzA(j + 512), w2x = swzA(j + 1024), w3x = swzA(j + 1536);
    dr[w0]  = o0.r; di[w0]  = o0.i;
    dr[w1x] = o1.r; di[w1x] = o1.i;
    dr[w2x] = o2.r; di[w2x] = o2.i;
    dr[w3x] = o3.r; di[w3x] = o3.i;
  }
}

__global__ __launch_bounds__(256) void kB(const float* __restrict__ qT,
                                          const float* __restrict__ kT,
                                          float* __restrict__ corrT) {
  __shared__ float Ar[L_], Ai[L_], Br[L_], Bi[L_];   // 32 KiB
  const int tid = threadIdx.x;
  const size_t row = (size_t)blockIdx.x * L_;

  const float4* q4 = (const float4*)(qT + row);
  const float4* k4 = (const float4*)(kT + row);
#pragma unroll
  for (int u = 0; u < 2; ++u) {
    const int idx = tid + (u << 8);          // float4 index
    const float4 vq = q4[idx];
    const float4 vk = k4[idx];
    const int a = swzA(idx << 2);            // low 2 bits preserved -> aligned
    *(float4*)&Ar[a] = vq;
    *(float4*)&Ai[a] = vk;
  }
  __syncthreads();

  // forward FFT: A -> B -> A -> B -> A
  pass8<0, false, true >(Ar, Ai, Br, Bi, tid); __syncthreads();
  pass8<3, false, false>(Br, Bi, Ar, Ai, tid); __syncthreads();
  pass8<6, false, true >(Ar, Ai, Br, Bi, tid); __syncthreads();
  pass4_final<false>    (Br, Bi, Ar, Ai, tid); __syncthreads();

  // cross-spectrum in place on A (reg-staged pairing f <-> N-f)
  {
    cf zf[8], zg[8];
#pragma unroll
    for (int u = 0; u < 8; ++u) {
      const int f = tid + (u << 8);
      const int g = (L_ - f) & (L_ - 1);
      const int sf = swzA(f), sg = swzA(g);
      zf[u] = {Ar[sf], Ai[sf]};
      zg[u] = {Ar[sg], Ai[sg]};
    }
    __syncthreads();
#pragma unroll
    for (int u = 0; u < 8; ++u) {
      const int f = tid + (u << 8);
      const float ar = zf[u].r, ai = zf[u].i, br = zg[u].r, bi = zg[u].i;
      const float qr = 0.5f * (ar + br), qi = 0.5f * (ai - bi);
      const float kr = 0.5f * (ai + bi), ki = 0.5f * (br - ar);
      const int sf = swzA(f);
      Ar[sf] = qr * kr + qi * ki;
      Ai[sf] = qi * kr - qr * ki;
    }
    __syncthreads();
  }

  // inverse FFT (conjugate twiddles): A -> B -> A -> B -> A
  pass8<0, true, true >(Ar, Ai, Br, Bi, tid); __syncthreads();
  pass8<3, true, false>(Br, Bi, Ar, Ai, tid); __syncthreads();
  pass8<6, true, true >(Ar, Ai, Br, Bi, tid); __syncthreads();
  pass4_final<true>     (Br, Bi, Ar, Ai, tid); __syncthreads();

  float4* c4 = (float4*)(corrT + row);
  const float inv = 1.0f / (float)L_;
#pragma unroll
  for (int u = 0; u < 2; ++u) {
    const int idx = tid + (u << 8);
    const int a = swzA(idx << 2);
    float4 vr = *(const float4*)&Ar[a];
    vr.x *= inv; vr.y *= inv; vr.z *= inv; vr.w *= inv;
    c4[idx] = vr;
  }
}

// ---------------------------------------------------------------------------
// Kernel C: transpose corrT (B,D,L) -> corr_out (B,L,D) + per-(b,dtile) sums.
// ---------------------------------------------------------------------------
__global__ __launch_bounds__(256) void kC(const float* __restrict__ corrT,
                                          float* __restrict__ corrOut,
                                          float* __restrict__ partial) {
  __shared__ float t[32][33];
  const int t0 = blockIdx.x * 32, d0 = blockIdx.y * 32, b = blockIdx.z;
  const int tx = threadIdx.x, ty = threadIdx.y;       // (32,8)
#pragma unroll
  for (int j = 0; j < 4; ++j) {
    const int d = d0 + ty + 8 * j;
    t[ty + 8 * j][tx] = corrT[((size_t)b * D_ + d) * L_ + t0 + tx];
  }
  __syncthreads();
#pragma unroll
  for (int j = 0; j < 4; ++j) {
    const int tt = t0 + ty + 8 * j;
    corrOut[((size_t)b * L_ + tt) * D_ + d0 + tx] = t[tx][ty + 8 * j];
  }
  if (ty == 0) {
    float s = 0.f;
#pragma unroll
    for (int i = 0; i < 32; ++i) s += t[i][tx];
    partial[((size_t)b * 16 + blockIdx.y) * L_ + t0 + tx] = s;
  }
}

// ---------------------------------------------------------------------------
// Kernel D0: reduce partial[256][L] -> g[L]  (32 blocks, deterministic)
// ---------------------------------------------------------------------------
__global__ __launch_bounds__(256) void kD0(const float* __restrict__ partial,
                                           float* __restrict__ g) {
  __shared__ float red[4][64];
  const int tl = threadIdx.x & 63, rg = threadIdx.x >> 6;
  const int tau = blockIdx.x * 64 + tl;
  float s = 0.f;
  for (int i = rg; i < 256; i += 4) s += partial[(size_t)i * L_ + tau];
  red[rg][tl] = s;
  __syncthreads();
  if (rg == 0) g[tau] = red[0][tl] + red[1][tl] + red[2][tl] + red[3][tl];
}

// ---------------------------------------------------------------------------
// Kernel D1: top-7 on g[L]; per-b softmax weights. Single small block.
// ---------------------------------------------------------------------------
__global__ __launch_bounds__(256) void kD1(const float* __restrict__ gin,
                                           const float* __restrict__ partial,
                                           int* __restrict__ oidx,
                                           float* __restrict__ ow) {
  __shared__ float g[L_];
  __shared__ float rv[256];
  __shared__ int   ri[256];
  __shared__ int   sidx[K_];
  const int tid = threadIdx.x;
#pragma unroll
  for (int u = 0; u < 8; ++u) g[tid + u * 256] = gin[tid + u * 256];
  __syncthreads();

  for (int it = 0; it < K_; ++it) {
    float bv = -1e30f; int bix = 1 << 30;
#pragma unroll
    for (int u = 0; u < 8; ++u) {
      const int tau = tid + u * 256;
      const float vv = g[tau];
      if (vv > bv || (vv == bv && tau < bix)) { bv = vv; bix = tau; }
    }
    rv[tid] = bv; ri[tid] = bix;
    __syncthreads();
    for (int off = 128; off > 0; off >>= 1) {
      if (tid < off) {
        const float v2 = rv[tid + off]; const int i2 = ri[tid + off];
        if (v2 > rv[tid] || (v2 == rv[tid] && i2 < ri[tid])) {
          rv[tid] = v2; ri[tid] = i2;
        }
      }
      __syncthreads();
    }
    if (tid == 0) { sidx[it] = ri[0]; g[ri[0]] = -3e38f; }
    __syncthreads();
  }

  if (tid < B_) {
    const int b = tid;
    float m[K_]; float mx = -1e30f;
    for (int kk = 0; kk < K_; ++kk) {
      float s = 0.f;
      for (int dt = 0; dt < 16; ++dt)
        s += partial[((size_t)b * 16 + dt) * L_ + sidx[kk]];
      m[kk] = s * (1.0f / 512.0f);
      mx = fmaxf(mx, m[kk]);
    }
    float sum = 0.f;
    for (int kk = 0; kk < K_; ++kk) { m[kk] = expf(m[kk] - mx); sum += m[kk]; }
    const float inv = 1.0f / sum;
    for (int kk = 0; kk < K_; ++kk) ow[b * K_ + kk] = m[kk] * inv;
  }
  if (tid < K_) oidx[tid] = sidx[tid];
}

// ---------------------------------------------------------------------------
// Kernel E: out[b,l,:] = sum_k w[b,k] * v[b, (l+idx[k])%L, :]   (float4)
// ---------------------------------------------------------------------------
__global__ __launch_bounds__(256) void kE(const float4* __restrict__ v4,
                                          const float* __restrict__ w,
                                          const int* __restrict__ idx,
                                          float4* __restrict__ out4) {
  const int bx = blockIdx.x;
  const int b  = bx >> 10;
  const int l  = ((bx & 1023) << 1) | (threadIdx.x >> 7);
  const int j  = threadIdx.x & 127;

  float ww[K_]; int rr[K_];
#pragma unroll
  for (int kk = 0; kk < K_; ++kk) {
    ww[kk] = w[b * K_ + kk];
    int r = l + idx[kk];
    if (r >= L_) r -= L_;
    rr[kk] = r;
  }
  const size_t vb = (size_t)b * L_ * 128;
  float4 acc = make_float4(0.f, 0.f, 0.f, 0.f);
#pragma unroll
  for (int kk = 0; kk < K_; ++kk) {
    const float4 vv = v4[vb + (size_t)rr[kk] * 128 + j];
    acc.x += ww[kk] * vv.x; acc.y += ww[kk] * vv.y;
    acc.z += ww[kk] * vv.z; acc.w += ww[kk] * vv.w;
  }
  out4[vb + (size_t)l * 128 + j] = acc;
}

// ---------------------------------------------------------------------------
extern "C" void kernel_launch(void* const* d_in, const int* in_sizes, int n_in,
                              void* d_out, int out_size, void* d_ws, size_t ws_size,
                              hipStream_t stream) {
  const float* q = (const float*)d_in[0];
  const float* k = (const float*)d_in[1];
  const float* v = (const float*)d_in[2];

  float* out     = (float*)d_out;        // final out  [0, Q_)
  float* corrOut = out + Q_;             // final corr [Q_, 2Q_)
  float* qT = out;                       // scratch: dead before kE overwrites
  float* kT = corrOut;                   // scratch: dead before kC overwrites

  float* corrT   = (float*)d_ws;                 // Q_ floats
  float* partial = corrT + Q_;                   // 524288 floats
  int*   oidx    = (int*)(partial + (size_t)B_ * 16 * L_);
  float* ow      = (float*)(oidx + 16);
  float* g2048   = corrT;                        // corrT dead after kC

  const dim3 thr(32, 8);
  kA<<<dim3(L_ / 32, D_ / 32, B_), thr, 0, stream>>>(q, k, qT, kT);
  kB<<<B_ * D_, 256, 0, stream>>>(qT, kT, corrT);
  kC<<<dim3(L_ / 32, D_ / 32, B_), thr, 0, stream>>>(corrT, corrOut, partial);
  kD0<<<32, 256, 0, stream>>>(partial, g2048);
  kD1<<<1, 256, 0, stream>>>(g2048, partial, oidx, ow);
  kE<<<(B_ * L_) / 2, 256, 0, stream>>>((const float4*)v, ow, oidx, (float4*)out);
}